// Round 5
// baseline (1117.357 us; speedup 1.0000x reference)
//
#include <hip/hip_runtime.h>
#include <hip/hip_fp16.h>
#include <math.h>

#define BS 256
static constexpr int NN = 100000;   // nodes
static constexpr int EE = 1600000;  // directed edges (excl. self loops)
static constexpr int SCAN_ELEMS = 1024;           // elements per scan block
static constexpr int SCAN_NB = (NN + SCAN_ELEMS - 1) / SCAN_ELEMS;  // 98
static constexpr int BUCKET_SH = 7;               // 128 nodes per bucket
static constexpr int NBUCKET = (NN + 127) >> BUCKET_SH;  // 782

static inline int cdiv(long long a, int b) { return (int)((a + b - 1) / b); }

// ---------------- helpers ----------------
template <int ACT>
__device__ __forceinline__ float act_f(float v) {
    if (ACT == 1) return fmaxf(v, 0.0f);
    if (ACT == 2) return tanhf(v);
    return v;
}

__device__ __forceinline__ unsigned short h16(float v) {
    return __half_as_ushort(__float2half(v));
}
__device__ __forceinline__ unsigned pack2h(float a, float b) {
    return (unsigned)h16(a) | ((unsigned)h16(b) << 16);
}
__device__ __forceinline__ float4 cvt4h(uint2 r) {
    float2 fa = __half22float2(*(const __half2*)&r.x);
    float2 fb = __half22float2(*(const __half2*)&r.y);
    return make_float4(fa.x, fa.y, fb.x, fb.y);
}

// OUTM: 0 = plain fp32, 1 = fp32 * dis[n], 2 = fp16 * dis[n] (ushort* buffer)
template <int OUTM>
__device__ __forceinline__ void store1(float* out, size_t idx, float v, float dn) {
    if (OUTM == 0) out[idx] = v;
    else if (OUTM == 1) out[idx] = v * dn;
    else ((unsigned short*)out)[idx] = h16(v * dn);
}

// ---------------- CSR build ----------------
__global__ void k_zero(int* __restrict__ cnt) {
    int i = blockIdx.x * BS + threadIdx.x;
    if (i < NN) cnt[i] = 0;
}

__global__ void k_count(const int* __restrict__ dst, int* __restrict__ cnt) {
    int e = blockIdx.x * BS + threadIdx.x;
    if (e < EE) atomicAdd(&cnt[dst[e]], 1);
}

__global__ void k_deg(const int* __restrict__ cnt, float* __restrict__ dis) {
    int i = blockIdx.x * BS + threadIdx.x;
    if (i < NN) dis[i] = rsqrtf((float)(cnt[i] + 1));  // + self loop
}

__global__ void k_scan1(const int* __restrict__ cnt, int* __restrict__ outp,
                        int* __restrict__ bsums) {
    __shared__ int lds[BS];
    int base = blockIdx.x * SCAN_ELEMS;
    int t = threadIdx.x;
    int v[4];
    int s = 0;
#pragma unroll
    for (int j = 0; j < 4; ++j) {
        int idx = base + t * 4 + j;
        v[j] = (idx < NN) ? cnt[idx] : 0;
        s += v[j];
    }
    lds[t] = s;
    __syncthreads();
    for (int off = 1; off < BS; off <<= 1) {
        int add = (t >= off) ? lds[t - off] : 0;
        __syncthreads();
        lds[t] += add;
        __syncthreads();
    }
    int run = lds[t] - s;
    if (t == BS - 1) bsums[blockIdx.x] = lds[BS - 1];
#pragma unroll
    for (int j = 0; j < 4; ++j) {
        int idx = base + t * 4 + j;
        if (idx < NN) outp[idx] = run;
        run += v[j];
    }
}

__global__ void k_scan2(int* __restrict__ bsums) {
    if (blockIdx.x == 0 && threadIdx.x == 0) {
        int acc = 0;
        for (int i = 0; i < SCAN_NB; ++i) {
            int t = bsums[i];
            bsums[i] = acc;
            acc += t;
        }
    }
}

// finalize rowptr; also init coarse bucket cursors (ccur[b] = rowptr[b*128])
__global__ void k_scan3(int* __restrict__ rowptr, const int* __restrict__ bsums,
                        int* __restrict__ ccur) {
    int i = blockIdx.x * BS + threadIdx.x;
    if (i < NN) {
        int r = rowptr[i] + bsums[i / SCAN_ELEMS];
        rowptr[i] = r;
        if ((i & ((1 << BUCKET_SH) - 1)) == 0) ccur[i >> BUCKET_SH] = r;
    }
    if (i == 0) rowptr[NN] = EE;
}

// pass A: coarse scatter into bucket regions; payload = (dst&127)<<17 | src
__global__ void k_bucket(const int* __restrict__ src, const int* __restrict__ dst,
                         int* __restrict__ ccur, unsigned* __restrict__ epb) {
    int e = blockIdx.x * BS + threadIdx.x;
    if (e >= EE) return;
    int d = dst[e];
    int b = d >> BUCKET_SH;
    int pos = atomicAdd(&ccur[b], 1);
    epb[pos] = ((unsigned)(d & ((1 << BUCKET_SH) - 1)) << 17) | (unsigned)src[e];
}

// pass B: within-bucket exact CSR placement via LDS cursors
__global__ __launch_bounds__(256) void k_fine(const int* __restrict__ rowptr,
                                              const unsigned* __restrict__ epb,
                                              int* __restrict__ eidx) {
    __shared__ int cur[1 << BUCKET_SH];
    int b = blockIdx.x;
    int n0 = b << BUCKET_SH;
    int n1 = min(n0 + (1 << BUCKET_SH), NN);
    int t = threadIdx.x;
    if (t < (n1 - n0)) cur[t] = rowptr[n0 + t];
    __syncthreads();
    int es = rowptr[n0], ee2 = rowptr[n1];
    for (int k = es + t; k < ee2; k += 256) {
        unsigned p = epb[k];
        int dl = p >> 17;
        int s = (int)(p & 0x1FFFFu);
        int pos = atomicAdd(&cur[dl], 1);
        eidx[pos] = s;
    }
}

// ---------------- gathers ----------------
// fp16 input g (= dis*h, fp16): out[n,:] = act( dis[n]*(g[n,:]+sum g[src,:]) + b )
template <int C, int ACT, bool HASB>
__global__ void k_gatherh(const unsigned short* __restrict__ g, const int* __restrict__ rowptr,
                          const int* __restrict__ eidx, const float* __restrict__ dis,
                          const float* __restrict__ b, float* __restrict__ out) {
    static_assert(C % 4 == 0, "C%4");
    constexpr int V = C / 4;
    int t = blockIdx.x * BS + threadIdx.x;
    if (t >= NN * V) return;
    int n = t / V, v = t % V;
    const uint2* g2 = (const uint2*)g;
    float4 acc = cvt4h(g2[(size_t)n * V + v]);  // self term
    int rs = rowptr[n], re = rowptr[n + 1];
    for (int k = rs; k < re; ++k) {
        int s = eidx[k];
        float4 hv = cvt4h(g2[(size_t)s * V + v]);
        acc.x += hv.x; acc.y += hv.y; acc.z += hv.z; acc.w += hv.w;
    }
    float dn = dis[n];
    acc.x *= dn; acc.y *= dn; acc.z *= dn; acc.w *= dn;
    if (HASB) {
        float4 bb = ((const float4*)b)[v];
        acc.x += bb.x; acc.y += bb.y; acc.z += bb.z; acc.w += bb.w;
    }
    acc.x = act_f<ACT>(acc.x);
    acc.y = act_f<ACT>(acc.y);
    acc.z = act_f<ACT>(acc.z);
    acc.w = act_f<ACT>(acc.w);
    ((float4*)out)[(size_t)n * V + v] = acc;
}

// fp32 3-channel gather (input g = dis*h fp32)
template <int ACT, bool HASB>
__global__ void k_gather3d(const float* __restrict__ g, const int* __restrict__ rowptr,
                           const int* __restrict__ eidx, const float* __restrict__ dis,
                           const float* __restrict__ b, float* __restrict__ out) {
    int n = blockIdx.x * BS + threadIdx.x;
    if (n >= NN) return;
    const float* gp = g + (size_t)n * 3;
    float a0 = gp[0], a1 = gp[1], a2 = gp[2];
    int rs = rowptr[n], re = rowptr[n + 1];
    for (int k = rs; k < re; ++k) {
        const float* gq = g + (size_t)eidx[k] * 3;
        a0 += gq[0]; a1 += gq[1]; a2 += gq[2];
    }
    float dn = dis[n];
    a0 *= dn; a1 *= dn; a2 *= dn;
    if (HASB) { a0 += b[0]; a1 += b[1]; a2 += b[2]; }
    float* op = out + (size_t)n * 3;
    op[0] = act_f<ACT>(a0);
    op[1] = act_f<ACT>(a1);
    op[2] = act_f<ACT>(a2);
}

// prescale: g = x * dis[n] (3ch fp32)
__global__ void k_scale3(const float* __restrict__ x, const float* __restrict__ dis,
                         float* __restrict__ g) {
    int i = blockIdx.x * BS + threadIdx.x;
    if (i < NN * 3) g[i] = x[i] * dis[i / 3];
}

// ---------------- LDS-tiled SGEMM ----------------
template <int CIN, int COUT, int TC, int TN, int TM, int BK, int ACT, bool HASB, int OUTM>
__global__ __launch_bounds__(256) void k_mm_tiled(const float* __restrict__ x,
                                                  const float* __restrict__ w,
                                                  const float* __restrict__ b,
                                                  float* __restrict__ out,
                                                  const float* __restrict__ dis) {
    constexpr int TR = 256 / TC;
    constexpr int BM = TR * TM;
    constexpr int LDA = BM + 4;
    constexpr int CHUNKS = CIN / BK;
    constexpr int BK4 = BK / 4;
    constexpr int CIN4 = CIN / 4;
    static_assert(TC * TN == COUT, "cols");
    static_assert(CIN % BK == 0 && BK % 4 == 0, "bk");
    static_assert(TM == 4 || TM == 8, "tm");
    __shared__ float As[BK * LDA];
    __shared__ float Ws[BK * COUT];
    const int tid = threadIdx.x;
    const int tc = tid % TC, tr = tid / TC;
    const int n0 = blockIdx.x * BM;

    float acc[TM][TN];
#pragma unroll
    for (int r = 0; r < TM; ++r)
#pragma unroll
        for (int j = 0; j < TN; ++j) acc[r][j] = HASB ? b[tc * TN + j] : 0.0f;

    const float4* x4 = (const float4*)x;
    const float4* w4 = (const float4*)w;

    for (int ch = 0; ch < CHUNKS; ++ch) {
        const int kb4 = ch * BK4;
        if (ch) __syncthreads();
        for (int i = tid; i < BM * BK4; i += 256) {
            int r = i / BK4, k4 = i % BK4;
            int row = n0 + r;
            float4 v = make_float4(0.f, 0.f, 0.f, 0.f);
            if (row < NN) v = x4[(size_t)row * CIN4 + kb4 + k4];
            int base = (4 * k4) * LDA + r;
            As[base] = v.x;
            As[base + LDA] = v.y;
            As[base + 2 * LDA] = v.z;
            As[base + 3 * LDA] = v.w;
        }
        for (int i = tid; i < BK * COUT / 4; i += 256) {
            ((float4*)Ws)[i] = w4[(size_t)kb4 * COUT + i];
        }
        __syncthreads();
#pragma unroll 4
        for (int k = 0; k < BK; ++k) {
            float a[TM];
            *(float4*)&a[0] = *(const float4*)&As[k * LDA + tr * TM];
            if (TM == 8) *(float4*)&a[4] = *(const float4*)&As[k * LDA + tr * TM + 4];
            float wr[TN];
#pragma unroll
            for (int j = 0; j < TN; ++j) wr[j] = Ws[k * COUT + tc * TN + j];
#pragma unroll
            for (int r = 0; r < TM; ++r)
#pragma unroll
                for (int j = 0; j < TN; ++j) acc[r][j] = fmaf(a[r], wr[j], acc[r][j]);
        }
    }
#pragma unroll
    for (int r = 0; r < TM; ++r) {
        int row = n0 + tr * TM + r;
        if (row < NN) {
            float dn = (OUTM != 0) ? dis[row] : 0.0f;
            size_t base = (size_t)row * COUT + tc * TN;
#pragma unroll
            for (int j = 0; j < TN; ++j) store1<OUTM>(out, base + j, act_f<ACT>(acc[r][j]), dn);
        }
    }
}

// ---------------- mm_vec4: TM=8 rows x 4 cols per thread ----------------
template <int CIN, int COUT, int ACT, bool HASB, int OUTM>
__global__ void k_mm_vec4(const float* __restrict__ x, const float* __restrict__ w,
                          const float* __restrict__ b, float* __restrict__ out,
                          const float* __restrict__ dis) {
    static_assert(CIN % 4 == 0 && COUT % 4 == 0, "align");
    constexpr int TM = 8;
    constexpr int CIN4 = CIN / 4;
    constexpr int COUT4 = COUT / 4;
    constexpr int RG = NN / TM;
    int i = blockIdx.x * BS + threadIdx.x;
    if (i >= RG * COUT4) return;
    int c4 = i % COUT4;
    int n0 = (i / COUT4) * TM;
    const float4* x4 = (const float4*)x;
    const float4* w4 = (const float4*)w;
    float4 acc[TM];
    float4 bb = HASB ? ((const float4*)b)[c4] : make_float4(0.f, 0.f, 0.f, 0.f);
#pragma unroll
    for (int r = 0; r < TM; ++r) acc[r] = bb;
    for (int k4 = 0; k4 < CIN4; ++k4) {
        float4 wv[4];
#pragma unroll
        for (int j = 0; j < 4; ++j) wv[j] = w4[(size_t)(4 * k4 + j) * COUT4 + c4];
#pragma unroll
        for (int r = 0; r < TM; ++r) {
            float4 xv = x4[(size_t)(n0 + r) * CIN4 + k4];
            acc[r].x = fmaf(xv.x, wv[0].x, fmaf(xv.y, wv[1].x, fmaf(xv.z, wv[2].x, fmaf(xv.w, wv[3].x, acc[r].x))));
            acc[r].y = fmaf(xv.x, wv[0].y, fmaf(xv.y, wv[1].y, fmaf(xv.z, wv[2].y, fmaf(xv.w, wv[3].y, acc[r].y))));
            acc[r].z = fmaf(xv.x, wv[0].z, fmaf(xv.y, wv[1].z, fmaf(xv.z, wv[2].z, fmaf(xv.w, wv[3].z, acc[r].z))));
            acc[r].w = fmaf(xv.x, wv[0].w, fmaf(xv.y, wv[1].w, fmaf(xv.z, wv[2].w, fmaf(xv.w, wv[3].w, acc[r].w))));
        }
    }
#pragma unroll
    for (int r = 0; r < TM; ++r) {
        float vx = act_f<ACT>(acc[r].x), vy = act_f<ACT>(acc[r].y);
        float vz = act_f<ACT>(acc[r].z), vw = act_f<ACT>(acc[r].w);
        size_t gi = (size_t)(n0 + r) * COUT4 + c4;
        if (OUTM == 2) {
            float dn = dis[n0 + r];
            uint2 u;
            u.x = pack2h(vx * dn, vy * dn);
            u.y = pack2h(vz * dn, vw * dn);
            ((uint2*)out)[gi] = u;
        } else if (OUTM == 1) {
            float dn = dis[n0 + r];
            ((float4*)out)[gi] = make_float4(vx * dn, vy * dn, vz * dn, vw * dn);
        } else {
            ((float4*)out)[gi] = make_float4(vx, vy, vz, vw);
        }
    }
}

// ---------------- small-CIN matmul, float4 output ----------------
template <int CIN, int COUT, int ACT>
__global__ void k_mm_rowbcast(const float* __restrict__ x, const float* __restrict__ w,
                              const float* __restrict__ b, float* __restrict__ out) {
    static_assert(COUT % 4 == 0, "c4");
    constexpr int COUT4 = COUT / 4;
    int i = blockIdx.x * BS + threadIdx.x;
    if (i >= NN * COUT4) return;
    int n = i / COUT4, c4 = i % COUT4;
    const float4* w4 = (const float4*)w;
    float4 acc = ((const float4*)b)[c4];
    const float* xr = x + (size_t)n * CIN;
#pragma unroll
    for (int ci = 0; ci < CIN; ++ci) {
        float xv = xr[ci];
        float4 wv = w4[ci * COUT4 + c4];
        acc.x = fmaf(xv, wv.x, acc.x);
        acc.y = fmaf(xv, wv.y, acc.y);
        acc.z = fmaf(xv, wv.z, acc.z);
        acc.w = fmaf(xv, wv.w, acc.w);
    }
    acc.x = act_f<ACT>(acc.x); acc.y = act_f<ACT>(acc.y);
    acc.z = act_f<ACT>(acc.z); acc.w = act_f<ACT>(acc.w);
    ((float4*)out)[(size_t)n * COUT4 + c4] = acc;
}

// ---------------- simple matmul (tiny layers) ----------------
template <int CIN, int COUT, int ACT, bool HASB, int OUTM>
__global__ void k_mm_simple(const float* __restrict__ x, const float* __restrict__ w,
                            const float* __restrict__ b, float* __restrict__ out,
                            const float* __restrict__ dis) {
    int i = blockIdx.x * BS + threadIdx.x;
    if (i >= NN * COUT) return;
    int n = i / COUT, c = i % COUT;
    const float* xr = x + (size_t)n * CIN;
    float acc = HASB ? b[c] : 0.0f;
#pragma unroll
    for (int ci = 0; ci < CIN; ++ci) acc = fmaf(xr[ci], w[ci * COUT + c], acc);
    float dn = (OUTM != 0) ? dis[n] : 0.0f;
    store1<OUTM>(out, (size_t)i, act_f<ACT>(acc), dn);
}

// ---------------- vec matmul (odd COUT) ----------------
template <int CIN, int COUT, int ACT, bool HASB, int OUTM>
__global__ void k_mm_vec(const float* __restrict__ x, const float* __restrict__ w,
                         const float* __restrict__ b, float* __restrict__ out,
                         const float* __restrict__ dis) {
    static_assert(CIN % 4 == 0, "CIN%4");
    constexpr int TM = 8;
    constexpr int CIN4 = CIN / 4;
    constexpr int RG = NN / TM;
    int i = blockIdx.x * BS + threadIdx.x;
    if (i >= RG * COUT) return;
    int c = i % COUT;
    int n0 = (i / COUT) * TM;
    float acc[TM];
    float bb = HASB ? b[c] : 0.0f;
#pragma unroll
    for (int r = 0; r < TM; ++r) acc[r] = bb;
    const float4* x4 = (const float4*)x;
    for (int k = 0; k < CIN4; ++k) {
        float w0 = w[(4 * k + 0) * COUT + c];
        float w1 = w[(4 * k + 1) * COUT + c];
        float w2 = w[(4 * k + 2) * COUT + c];
        float w3 = w[(4 * k + 3) * COUT + c];
#pragma unroll
        for (int r = 0; r < TM; ++r) {
            float4 xv = x4[(size_t)(n0 + r) * CIN4 + k];
            acc[r] = fmaf(xv.x, w0, fmaf(xv.y, w1, fmaf(xv.z, w2, fmaf(xv.w, w3, acc[r]))));
        }
    }
#pragma unroll
    for (int r = 0; r < TM; ++r) {
        int row = n0 + r;
        float dn = (OUTM != 0) ? dis[row] : 0.0f;
        store1<OUTM>(out, (size_t)row * COUT + c, act_f<ACT>(acc[r]), dn);
    }
}

extern "C" void kernel_launch(void* const* d_in, const int* in_sizes, int n_in,
                              void* d_out, int out_size, void* d_ws, size_t ws_size,
                              hipStream_t stream) {
    const float* x = (const float*)d_in[0];
    const int* ei = (const int*)d_in[1];
    const int* src = ei;
    const int* dst = ei + EE;
    const float* eg1_w = (const float*)d_in[2];  const float* eg1_b = (const float*)d_in[3];
    const float* eg2_w = (const float*)d_in[4];  const float* eg2_b = (const float*)d_in[5];
    const float* eg3_w = (const float*)d_in[6];  const float* eg3_b = (const float*)d_in[7];
    const float* eg4_w = (const float*)d_in[8];  const float* eg4_b = (const float*)d_in[9];
    const float* el1_w = (const float*)d_in[10]; const float* el1_b = (const float*)d_in[11];
    const float* el2_w = (const float*)d_in[12]; const float* el2_b = (const float*)d_in[13];
    const float* dl1_w = (const float*)d_in[14]; const float* dl1_b = (const float*)d_in[15];
    const float* dl2_w = (const float*)d_in[16]; const float* dl2_b = (const float*)d_in[17];
    const float* dg1_w = (const float*)d_in[18]; const float* dg1_b = (const float*)d_in[19];
    const float* dg2_w = (const float*)d_in[20]; const float* dg2_b = (const float*)d_in[21];
    const float* dg3_w = (const float*)d_in[22]; const float* dg3_b = (const float*)d_in[23];
    const float* dg4_w = (const float*)d_in[24]; const float* dg4_b = (const float*)d_in[25];
    float* out = (float*)d_out;

    char* ws = (char*)d_ws;
    size_t off = 0;
    auto alloc = [&](size_t bytes) {
        void* p = ws + off;
        off += (bytes + 15) & ~(size_t)15;
        return p;
    };
    int* cnt    = (int*)alloc(sizeof(int) * NN);
    int* rowptr = (int*)alloc(sizeof(int) * (NN + 1));
    int* ccur   = (int*)alloc(sizeof(int) * NBUCKET);
    int* bsums  = (int*)alloc(sizeof(int) * SCAN_NB);
    float* dis  = (float*)alloc(sizeof(float) * NN);
    int* eidx   = (int*)alloc(sizeof(int) * EE);
    unsigned* epb = (unsigned*)alloc(sizeof(unsigned) * EE);
    unsigned short* G = (unsigned short*)alloc(sizeof(unsigned short) * 80 * (size_t)NN);
    float* bufA = (float*)alloc(sizeof(float) * 160 * (size_t)NN);
    float* bufB = (float*)alloc(sizeof(float) * 160 * (size_t)NN);

    // ---- CSR build (bucketed counting sort) ----
    k_zero<<<cdiv(NN, BS), BS, 0, stream>>>(cnt);
    k_count<<<cdiv(EE, BS), BS, 0, stream>>>(dst, cnt);
    k_deg<<<cdiv(NN, BS), BS, 0, stream>>>(cnt, dis);
    k_scan1<<<SCAN_NB, BS, 0, stream>>>(cnt, rowptr, bsums);
    k_scan2<<<1, 64, 0, stream>>>(bsums);
    k_scan3<<<cdiv(NN, BS), BS, 0, stream>>>(rowptr, bsums, ccur);
    k_bucket<<<cdiv(EE, BS), BS, 0, stream>>>(src, dst, ccur, epb);
    k_fine<<<NBUCKET, 256, 0, stream>>>(rowptr, epb, eidx);

    // ---- eg1 (3->160): AGG-first ----
    k_scale3<<<cdiv(3LL * NN, BS), BS, 0, stream>>>(x, dis, bufB);
    k_gather3d<0, false><<<cdiv(NN, BS), BS, 0, stream>>>(bufB, rowptr, eidx, dis, nullptr, bufA);
    k_mm_rowbcast<3, 160, 1><<<cdiv(NN * 40LL, BS), BS, 0, stream>>>(bufA, eg1_w, eg1_b, bufB);

    // ---- eg2 (160->80): MM-first, fp16 g ----
    k_mm_tiled<160, 80, 16, 5, 8, 32, 0, false, 2><<<cdiv(NN, 128), 256, 0, stream>>>(
        bufB, eg2_w, nullptr, (float*)G, dis);
    k_gatherh<80, 1, true><<<cdiv(NN * 20LL, BS), BS, 0, stream>>>(G, rowptr, eidx, dis, eg2_b, bufA);

    // ---- eg3 (80->40): MM-first, fp16 g ----
    k_mm_tiled<80, 40, 8, 5, 4, 40, 0, false, 2><<<cdiv(NN, 128), 256, 0, stream>>>(
        bufA, eg3_w, nullptr, (float*)G, dis);
    k_gatherh<40, 1, true><<<cdiv(NN * 10LL, BS), BS, 0, stream>>>(G, rowptr, eidx, dis, eg3_b, bufB);

    // ---- eg4 (40->20): MM-first, fp16 g ----
    k_mm_vec4<40, 20, 0, false, 2><<<cdiv((NN / 8) * 5LL, BS), BS, 0, stream>>>(
        bufB, eg4_w, nullptr, (float*)G, dis);
    k_gatherh<20, 1, true><<<cdiv(NN * 5LL, BS), BS, 0, stream>>>(G, rowptr, eidx, dis, eg4_b, bufA);

    // ---- dense latent stack ----
    k_mm_vec<20, 10, 1, true, 0><<<cdiv((NN / 8) * 10LL, BS), BS, 0, stream>>>(bufA, el1_w, el1_b, bufB, nullptr);
    k_mm_simple<10, 3, 0, true, 0><<<cdiv(3LL * NN, BS), BS, 0, stream>>>(bufB, el2_w, el2_b, bufA, nullptr);
    k_mm_simple<3, 10, 1, true, 0><<<cdiv(10LL * NN, BS), BS, 0, stream>>>(bufA, dl1_w, dl1_b, bufB, nullptr);
    // dl2 (10->20): relu output scaled by dis -> fp16 g for dg1's gather
    k_mm_simple<10, 20, 1, true, 2><<<cdiv(20LL * NN, BS), BS, 0, stream>>>(bufB, dl2_w, dl2_b, (float*)G, dis);

    // ---- dg1 (20->40): AGG-first ----
    k_gatherh<20, 0, false><<<cdiv(NN * 5LL, BS), BS, 0, stream>>>(G, rowptr, eidx, dis, nullptr, bufA);
    k_mm_vec4<20, 40, 1, true, 2><<<cdiv((NN / 8) * 10LL, BS), BS, 0, stream>>>(
        bufA, dg1_w, dg1_b, (float*)G, dis);

    // ---- dg2 (40->80): AGG-first ----
    k_gatherh<40, 0, false><<<cdiv(NN * 10LL, BS), BS, 0, stream>>>(G, rowptr, eidx, dis, nullptr, bufB);
    k_mm_tiled<40, 80, 16, 5, 8, 40, 1, true, 2><<<cdiv(NN, 128), 256, 0, stream>>>(
        bufB, dg2_w, dg2_b, (float*)G, dis);

    // ---- dg3 (80->160): AGG-first ----
    k_gatherh<80, 0, false><<<cdiv(NN * 20LL, BS), BS, 0, stream>>>(G, rowptr, eidx, dis, nullptr, bufA);
    k_mm_tiled<80, 160, 32, 5, 8, 40, 1, true, 0><<<cdiv(NN, 64), 256, 0, stream>>>(
        bufA, dg3_w, dg3_b, bufB, nullptr);

    // ---- dg4 (160->3): MM-first, tanh; mm writes dis-scaled fp32 g ----
    k_mm_vec<160, 3, 0, false, 1><<<cdiv((NN / 8) * 3LL, BS), BS, 0, stream>>>(bufB, dg4_w, nullptr, bufA, dis);
    k_gather3d<2, true><<<cdiv(NN, BS), BS, 0, stream>>>(bufA, rowptr, eidx, dis, dg4_b, out);
}

// Round 6
// 705.679 us; speedup vs baseline: 1.5834x; 1.5834x over previous
//
#include <hip/hip_runtime.h>
#include <hip/hip_fp16.h>
#include <math.h>

#define BS 256
static constexpr int NN = 100000;   // nodes
static constexpr int EE = 1600000;  // directed edges (excl. self loops)
static constexpr int BUCKET_SH = 7;                       // 128 nodes per bucket
static constexpr int NBUCKET = (NN + 127) >> BUCKET_SH;   // 782
static constexpr int NB_PART = 256;                       // partition blocks
static constexpr int CHUNK = EE / NB_PART;                // 6250 (exact)
static constexpr int NP = NBUCKET * NB_PART;              // 200192 scan elems
static constexpr int SCAN_ELEMS = 1024;
static constexpr int NPB = (NP + SCAN_ELEMS - 1) / SCAN_ELEMS;  // 196

static inline int cdiv(long long a, int b) { return (int)((a + b - 1) / b); }

// ---------------- helpers ----------------
template <int ACT>
__device__ __forceinline__ float act_f(float v) {
    if (ACT == 1) return fmaxf(v, 0.0f);
    if (ACT == 2) return tanhf(v);
    return v;
}

__device__ __forceinline__ unsigned short h16(float v) {
    return __half_as_ushort(__float2half(v));
}
__device__ __forceinline__ unsigned pack2h(float a, float b) {
    return (unsigned)h16(a) | ((unsigned)h16(b) << 16);
}
__device__ __forceinline__ float4 cvt4h(uint2 r) {
    float2 fa = __half22float2(*(const __half2*)&r.x);
    float2 fb = __half22float2(*(const __half2*)&r.y);
    return make_float4(fa.x, fa.y, fb.x, fb.y);
}

// OUTM: 0 = plain fp32, 1 = fp32 * dis[n], 2 = fp16 * dis[n] (ushort* buffer)
template <int OUTM>
__device__ __forceinline__ void store1(float* out, size_t idx, float v, float dn) {
    if (OUTM == 0) out[idx] = v;
    else if (OUTM == 1) out[idx] = v * dn;
    else ((unsigned short*)out)[idx] = h16(v * dn);
}

// ---------------- CSR build: contention-free partitioned counting sort ----------------
// pass 1: per-partition LDS histogram of buckets
__global__ __launch_bounds__(256) void k_hist(const int* __restrict__ dst,
                                              int* __restrict__ part_cnt) {
    __shared__ int h[NBUCKET];
    int b = blockIdx.x;
    for (int j = threadIdx.x; j < NBUCKET; j += 256) h[j] = 0;
    __syncthreads();
    int e0 = b * CHUNK;
    for (int k = threadIdx.x; k < CHUNK; k += 256)
        atomicAdd(&h[dst[e0 + k] >> BUCKET_SH], 1);
    __syncthreads();
    for (int j = threadIdx.x; j < NBUCKET; j += 256)
        part_cnt[j * NB_PART + b] = h[j];   // bucket-major for the scan
}

// scan over NP elems: block-local (1024/block), then serial block-sum scan, then add-back
__global__ void k_scanA(const int* __restrict__ in, int* __restrict__ outp,
                        int* __restrict__ bsums) {
    __shared__ int lds[BS];
    int base = blockIdx.x * SCAN_ELEMS;
    int t = threadIdx.x;
    int v[4];
    int s = 0;
#pragma unroll
    for (int j = 0; j < 4; ++j) {
        int idx = base + t * 4 + j;
        v[j] = (idx < NP) ? in[idx] : 0;
        s += v[j];
    }
    lds[t] = s;
    __syncthreads();
    for (int off = 1; off < BS; off <<= 1) {
        int add = (t >= off) ? lds[t - off] : 0;
        __syncthreads();
        lds[t] += add;
        __syncthreads();
    }
    int run = lds[t] - s;
    if (t == BS - 1) bsums[blockIdx.x] = lds[BS - 1];
#pragma unroll
    for (int j = 0; j < 4; ++j) {
        int idx = base + t * 4 + j;
        if (idx < NP) outp[idx] = run;
        run += v[j];
    }
}

__global__ void k_scanB(int* __restrict__ bsums) {
    if (threadIdx.x == 0 && blockIdx.x == 0) {
        int acc = 0;
        for (int i = 0; i < NPB; ++i) {
            int t = bsums[i];
            bsums[i] = acc;
            acc += t;
        }
    }
}

// add-back; also emit bucket bases (element (j,b=0) holds bucket j's base)
__global__ void k_scanC(int* __restrict__ outp, const int* __restrict__ bsums,
                        int* __restrict__ bbase) {
    int i = blockIdx.x * BS + threadIdx.x;
    if (i < NP) {
        int v = outp[i] + bsums[i / SCAN_ELEMS];
        outp[i] = v;
        if ((i & (NB_PART - 1)) == 0) bbase[i / NB_PART] = v;
    }
    if (i == 0) bbase[NBUCKET] = EE;
}

// pass 2: deterministic placement into bucket-sorted payload (LDS cursors only)
__global__ __launch_bounds__(256) void k_part(const int* __restrict__ src,
                                              const int* __restrict__ dst,
                                              const int* __restrict__ scan_out,
                                              unsigned* __restrict__ epb) {
    __shared__ int cur[NBUCKET];
    int b = blockIdx.x;
    for (int j = threadIdx.x; j < NBUCKET; j += 256) cur[j] = scan_out[j * NB_PART + b];
    __syncthreads();
    int e0 = b * CHUNK;
    for (int k = threadIdx.x; k < CHUNK; k += 256) {
        int e = e0 + k;
        int d = dst[e];
        int s = src[e];
        int pos = atomicAdd(&cur[d >> BUCKET_SH], 1);
        epb[pos] = ((unsigned)(d & ((1 << BUCKET_SH) - 1)) << 17) | (unsigned)s;
    }
}

// pass 3: per-bucket node histogram -> rowptr + dis (coalesced) + exact CSR placement
__global__ __launch_bounds__(256) void k_fine2(const int* __restrict__ bbase,
                                               const unsigned* __restrict__ epb,
                                               int* __restrict__ eidx,
                                               int* __restrict__ rowptr,
                                               float* __restrict__ dis) {
    __shared__ int hcnt[1 << BUCKET_SH];
    __shared__ int hoff[1 << BUCKET_SH];
    int b = blockIdx.x;
    int n0 = b << BUCKET_SH;
    int nloc = min(1 << BUCKET_SH, NN - n0);
    int t = threadIdx.x;
    if (t < (1 << BUCKET_SH)) hcnt[t] = 0;
    __syncthreads();
    int es = bbase[b], ee = bbase[b + 1];
    for (int k = es + t; k < ee; k += 256) atomicAdd(&hcnt[epb[k] >> 17], 1);
    __syncthreads();
    if (t < (1 << BUCKET_SH)) hoff[t] = hcnt[t];
    __syncthreads();
    for (int off = 1; off < (1 << BUCKET_SH); off <<= 1) {
        int add = (t >= off && t < (1 << BUCKET_SH)) ? hoff[t - off] : 0;
        __syncthreads();
        if (t < (1 << BUCKET_SH)) hoff[t] += add;
        __syncthreads();
    }
    // hoff inclusive -> exclusive = hoff - hcnt
    if (t < nloc) {
        int excl = hoff[t] - hcnt[t];
        rowptr[n0 + t] = es + excl;
        dis[n0 + t] = rsqrtf((float)(hcnt[t] + 1));  // + self loop
    }
    __syncthreads();
    if (t < (1 << BUCKET_SH)) hoff[t] = es + hoff[t] - hcnt[t];  // cursors
    __syncthreads();
    for (int k = es + t; k < ee; k += 256) {
        unsigned p = epb[k];
        int pos = atomicAdd(&hoff[p >> 17], 1);
        eidx[pos] = (int)(p & 0x1FFFFu);
    }
    if (b == NBUCKET - 1 && t == 0) rowptr[NN] = EE;
}

// ---------------- gathers ----------------
// fp16 input g (= dis*h, fp16): out[n,:] = act( dis[n]*(g[n,:]+sum g[src,:]) + b )
template <int C, int ACT, bool HASB>
__global__ void k_gatherh(const unsigned short* __restrict__ g, const int* __restrict__ rowptr,
                          const int* __restrict__ eidx, const float* __restrict__ dis,
                          const float* __restrict__ b, float* __restrict__ out) {
    static_assert(C % 4 == 0, "C%4");
    constexpr int V = C / 4;
    int t = blockIdx.x * BS + threadIdx.x;
    if (t >= NN * V) return;
    int n = t / V, v = t % V;
    const uint2* g2 = (const uint2*)g;
    float4 acc = cvt4h(g2[(size_t)n * V + v]);  // self term
    int rs = rowptr[n], re = rowptr[n + 1];
    for (int k = rs; k < re; ++k) {
        int s = eidx[k];
        float4 hv = cvt4h(g2[(size_t)s * V + v]);
        acc.x += hv.x; acc.y += hv.y; acc.z += hv.z; acc.w += hv.w;
    }
    float dn = dis[n];
    acc.x *= dn; acc.y *= dn; acc.z *= dn; acc.w *= dn;
    if (HASB) {
        float4 bb = ((const float4*)b)[v];
        acc.x += bb.x; acc.y += bb.y; acc.z += bb.z; acc.w += bb.w;
    }
    acc.x = act_f<ACT>(acc.x);
    acc.y = act_f<ACT>(acc.y);
    acc.z = act_f<ACT>(acc.z);
    acc.w = act_f<ACT>(acc.w);
    ((float4*)out)[(size_t)n * V + v] = acc;
}

// fp32 3-channel gather (input g = dis*h fp32)
template <int ACT, bool HASB>
__global__ void k_gather3d(const float* __restrict__ g, const int* __restrict__ rowptr,
                           const int* __restrict__ eidx, const float* __restrict__ dis,
                           const float* __restrict__ b, float* __restrict__ out) {
    int n = blockIdx.x * BS + threadIdx.x;
    if (n >= NN) return;
    const float* gp = g + (size_t)n * 3;
    float a0 = gp[0], a1 = gp[1], a2 = gp[2];
    int rs = rowptr[n], re = rowptr[n + 1];
    for (int k = rs; k < re; ++k) {
        const float* gq = g + (size_t)eidx[k] * 3;
        a0 += gq[0]; a1 += gq[1]; a2 += gq[2];
    }
    float dn = dis[n];
    a0 *= dn; a1 *= dn; a2 *= dn;
    if (HASB) { a0 += b[0]; a1 += b[1]; a2 += b[2]; }
    float* op = out + (size_t)n * 3;
    op[0] = act_f<ACT>(a0);
    op[1] = act_f<ACT>(a1);
    op[2] = act_f<ACT>(a2);
}

// prescale: g = x * dis[n] (3ch fp32)
__global__ void k_scale3(const float* __restrict__ x, const float* __restrict__ dis,
                         float* __restrict__ g) {
    int i = blockIdx.x * BS + threadIdx.x;
    if (i < NN * 3) g[i] = x[i] * dis[i / 3];
}

// ---------------- LDS-tiled SGEMM ----------------
template <int CIN, int COUT, int TC, int TN, int TM, int BK, int ACT, bool HASB, int OUTM>
__global__ __launch_bounds__(256) void k_mm_tiled(const float* __restrict__ x,
                                                  const float* __restrict__ w,
                                                  const float* __restrict__ b,
                                                  float* __restrict__ out,
                                                  const float* __restrict__ dis) {
    constexpr int TR = 256 / TC;
    constexpr int BM = TR * TM;
    constexpr int LDA = BM + 4;
    constexpr int CHUNKS = CIN / BK;
    constexpr int BK4 = BK / 4;
    constexpr int CIN4 = CIN / 4;
    static_assert(TC * TN == COUT, "cols");
    static_assert(CIN % BK == 0 && BK % 4 == 0, "bk");
    static_assert(TM == 4 || TM == 8, "tm");
    __shared__ float As[BK * LDA];
    __shared__ float Ws[BK * COUT];
    const int tid = threadIdx.x;
    const int tc = tid % TC, tr = tid / TC;
    const int n0 = blockIdx.x * BM;

    float acc[TM][TN];
#pragma unroll
    for (int r = 0; r < TM; ++r)
#pragma unroll
        for (int j = 0; j < TN; ++j) acc[r][j] = HASB ? b[tc * TN + j] : 0.0f;

    const float4* x4 = (const float4*)x;
    const float4* w4 = (const float4*)w;

    for (int ch = 0; ch < CHUNKS; ++ch) {
        const int kb4 = ch * BK4;
        if (ch) __syncthreads();
        for (int i = tid; i < BM * BK4; i += 256) {
            int r = i / BK4, k4 = i % BK4;
            int row = n0 + r;
            float4 v = make_float4(0.f, 0.f, 0.f, 0.f);
            if (row < NN) v = x4[(size_t)row * CIN4 + kb4 + k4];
            int base = (4 * k4) * LDA + r;
            As[base] = v.x;
            As[base + LDA] = v.y;
            As[base + 2 * LDA] = v.z;
            As[base + 3 * LDA] = v.w;
        }
        for (int i = tid; i < BK * COUT / 4; i += 256) {
            ((float4*)Ws)[i] = w4[(size_t)kb4 * COUT + i];
        }
        __syncthreads();
#pragma unroll 4
        for (int k = 0; k < BK; ++k) {
            float a[TM];
            *(float4*)&a[0] = *(const float4*)&As[k * LDA + tr * TM];
            if (TM == 8) *(float4*)&a[4] = *(const float4*)&As[k * LDA + tr * TM + 4];
            float wr[TN];
#pragma unroll
            for (int j = 0; j < TN; ++j) wr[j] = Ws[k * COUT + tc * TN + j];
#pragma unroll
            for (int r = 0; r < TM; ++r)
#pragma unroll
                for (int j = 0; j < TN; ++j) acc[r][j] = fmaf(a[r], wr[j], acc[r][j]);
        }
    }
#pragma unroll
    for (int r = 0; r < TM; ++r) {
        int row = n0 + tr * TM + r;
        if (row < NN) {
            float dn = (OUTM != 0) ? dis[row] : 0.0f;
            size_t base = (size_t)row * COUT + tc * TN;
#pragma unroll
            for (int j = 0; j < TN; ++j) store1<OUTM>(out, base + j, act_f<ACT>(acc[r][j]), dn);
        }
    }
}

// ---------------- mm_vec4: TM=8 rows x 4 cols per thread ----------------
template <int CIN, int COUT, int ACT, bool HASB, int OUTM>
__global__ void k_mm_vec4(const float* __restrict__ x, const float* __restrict__ w,
                          const float* __restrict__ b, float* __restrict__ out,
                          const float* __restrict__ dis) {
    static_assert(CIN % 4 == 0 && COUT % 4 == 0, "align");
    constexpr int TM = 8;
    constexpr int CIN4 = CIN / 4;
    constexpr int COUT4 = COUT / 4;
    constexpr int RG = NN / TM;
    int i = blockIdx.x * BS + threadIdx.x;
    if (i >= RG * COUT4) return;
    int c4 = i % COUT4;
    int n0 = (i / COUT4) * TM;
    const float4* x4 = (const float4*)x;
    const float4* w4 = (const float4*)w;
    float4 acc[TM];
    float4 bb = HASB ? ((const float4*)b)[c4] : make_float4(0.f, 0.f, 0.f, 0.f);
#pragma unroll
    for (int r = 0; r < TM; ++r) acc[r] = bb;
    for (int k4 = 0; k4 < CIN4; ++k4) {
        float4 wv[4];
#pragma unroll
        for (int j = 0; j < 4; ++j) wv[j] = w4[(size_t)(4 * k4 + j) * COUT4 + c4];
#pragma unroll
        for (int r = 0; r < TM; ++r) {
            float4 xv = x4[(size_t)(n0 + r) * CIN4 + k4];
            acc[r].x = fmaf(xv.x, wv[0].x, fmaf(xv.y, wv[1].x, fmaf(xv.z, wv[2].x, fmaf(xv.w, wv[3].x, acc[r].x))));
            acc[r].y = fmaf(xv.x, wv[0].y, fmaf(xv.y, wv[1].y, fmaf(xv.z, wv[2].y, fmaf(xv.w, wv[3].y, acc[r].y))));
            acc[r].z = fmaf(xv.x, wv[0].z, fmaf(xv.y, wv[1].z, fmaf(xv.z, wv[2].z, fmaf(xv.w, wv[3].z, acc[r].z))));
            acc[r].w = fmaf(xv.x, wv[0].w, fmaf(xv.y, wv[1].w, fmaf(xv.z, wv[2].w, fmaf(xv.w, wv[3].w, acc[r].w))));
        }
    }
#pragma unroll
    for (int r = 0; r < TM; ++r) {
        float vx = act_f<ACT>(acc[r].x), vy = act_f<ACT>(acc[r].y);
        float vz = act_f<ACT>(acc[r].z), vw = act_f<ACT>(acc[r].w);
        size_t gi = (size_t)(n0 + r) * COUT4 + c4;
        if (OUTM == 2) {
            float dn = dis[n0 + r];
            uint2 u;
            u.x = pack2h(vx * dn, vy * dn);
            u.y = pack2h(vz * dn, vw * dn);
            ((uint2*)out)[gi] = u;
        } else if (OUTM == 1) {
            float dn = dis[n0 + r];
            ((float4*)out)[gi] = make_float4(vx * dn, vy * dn, vz * dn, vw * dn);
        } else {
            ((float4*)out)[gi] = make_float4(vx, vy, vz, vw);
        }
    }
}

// ---------------- small-CIN matmul, float4 output ----------------
template <int CIN, int COUT, int ACT>
__global__ void k_mm_rowbcast(const float* __restrict__ x, const float* __restrict__ w,
                              const float* __restrict__ b, float* __restrict__ out) {
    static_assert(COUT % 4 == 0, "c4");
    constexpr int COUT4 = COUT / 4;
    int i = blockIdx.x * BS + threadIdx.x;
    if (i >= NN * COUT4) return;
    int n = i / COUT4, c4 = i % COUT4;
    const float4* w4 = (const float4*)w;
    float4 acc = ((const float4*)b)[c4];
    const float* xr = x + (size_t)n * CIN;
#pragma unroll
    for (int ci = 0; ci < CIN; ++ci) {
        float xv = xr[ci];
        float4 wv = w4[ci * COUT4 + c4];
        acc.x = fmaf(xv, wv.x, acc.x);
        acc.y = fmaf(xv, wv.y, acc.y);
        acc.z = fmaf(xv, wv.z, acc.z);
        acc.w = fmaf(xv, wv.w, acc.w);
    }
    acc.x = act_f<ACT>(acc.x); acc.y = act_f<ACT>(acc.y);
    acc.z = act_f<ACT>(acc.z); acc.w = act_f<ACT>(acc.w);
    ((float4*)out)[(size_t)n * COUT4 + c4] = acc;
}

// ---------------- simple matmul (tiny layers) ----------------
template <int CIN, int COUT, int ACT, bool HASB, int OUTM>
__global__ void k_mm_simple(const float* __restrict__ x, const float* __restrict__ w,
                            const float* __restrict__ b, float* __restrict__ out,
                            const float* __restrict__ dis) {
    int i = blockIdx.x * BS + threadIdx.x;
    if (i >= NN * COUT) return;
    int n = i / COUT, c = i % COUT;
    const float* xr = x + (size_t)n * CIN;
    float acc = HASB ? b[c] : 0.0f;
#pragma unroll
    for (int ci = 0; ci < CIN; ++ci) acc = fmaf(xr[ci], w[ci * COUT + c], acc);
    float dn = (OUTM != 0) ? dis[n] : 0.0f;
    store1<OUTM>(out, (size_t)i, act_f<ACT>(acc), dn);
}

// ---------------- vec matmul (odd COUT) ----------------
template <int CIN, int COUT, int ACT, bool HASB, int OUTM>
__global__ void k_mm_vec(const float* __restrict__ x, const float* __restrict__ w,
                         const float* __restrict__ b, float* __restrict__ out,
                         const float* __restrict__ dis) {
    static_assert(CIN % 4 == 0, "CIN%4");
    constexpr int TM = 8;
    constexpr int CIN4 = CIN / 4;
    constexpr int RG = NN / TM;
    int i = blockIdx.x * BS + threadIdx.x;
    if (i >= RG * COUT) return;
    int c = i % COUT;
    int n0 = (i / COUT) * TM;
    float acc[TM];
    float bb = HASB ? b[c] : 0.0f;
#pragma unroll
    for (int r = 0; r < TM; ++r) acc[r] = bb;
    const float4* x4 = (const float4*)x;
    for (int k = 0; k < CIN4; ++k) {
        float w0 = w[(4 * k + 0) * COUT + c];
        float w1 = w[(4 * k + 1) * COUT + c];
        float w2 = w[(4 * k + 2) * COUT + c];
        float w3 = w[(4 * k + 3) * COUT + c];
#pragma unroll
        for (int r = 0; r < TM; ++r) {
            float4 xv = x4[(size_t)(n0 + r) * CIN4 + k];
            acc[r] = fmaf(xv.x, w0, fmaf(xv.y, w1, fmaf(xv.z, w2, fmaf(xv.w, w3, acc[r]))));
        }
    }
#pragma unroll
    for (int r = 0; r < TM; ++r) {
        int row = n0 + r;
        float dn = (OUTM != 0) ? dis[row] : 0.0f;
        store1<OUTM>(out, (size_t)row * COUT + c, act_f<ACT>(acc[r]), dn);
    }
}

extern "C" void kernel_launch(void* const* d_in, const int* in_sizes, int n_in,
                              void* d_out, int out_size, void* d_ws, size_t ws_size,
                              hipStream_t stream) {
    const float* x = (const float*)d_in[0];
    const int* ei = (const int*)d_in[1];
    const int* src = ei;
    const int* dst = ei + EE;
    const float* eg1_w = (const float*)d_in[2];  const float* eg1_b = (const float*)d_in[3];
    const float* eg2_w = (const float*)d_in[4];  const float* eg2_b = (const float*)d_in[5];
    const float* eg3_w = (const float*)d_in[6];  const float* eg3_b = (const float*)d_in[7];
    const float* eg4_w = (const float*)d_in[8];  const float* eg4_b = (const float*)d_in[9];
    const float* el1_w = (const float*)d_in[10]; const float* el1_b = (const float*)d_in[11];
    const float* el2_w = (const float*)d_in[12]; const float* el2_b = (const float*)d_in[13];
    const float* dl1_w = (const float*)d_in[14]; const float* dl1_b = (const float*)d_in[15];
    const float* dl2_w = (const float*)d_in[16]; const float* dl2_b = (const float*)d_in[17];
    const float* dg1_w = (const float*)d_in[18]; const float* dg1_b = (const float*)d_in[19];
    const float* dg2_w = (const float*)d_in[20]; const float* dg2_b = (const float*)d_in[21];
    const float* dg3_w = (const float*)d_in[22]; const float* dg3_b = (const float*)d_in[23];
    const float* dg4_w = (const float*)d_in[24]; const float* dg4_b = (const float*)d_in[25];
    float* out = (float*)d_out;

    char* ws = (char*)d_ws;
    size_t off = 0;
    auto alloc = [&](size_t bytes) {
        void* p = ws + off;
        off += (bytes + 15) & ~(size_t)15;
        return p;
    };
    int* part_cnt = (int*)alloc(sizeof(int) * NP);
    int* scan_out = (int*)alloc(sizeof(int) * NP);
    int* bsums    = (int*)alloc(sizeof(int) * NPB);
    int* bbase    = (int*)alloc(sizeof(int) * (NBUCKET + 1));
    int* rowptr   = (int*)alloc(sizeof(int) * (NN + 1));
    float* dis    = (float*)alloc(sizeof(float) * NN);
    int* eidx     = (int*)alloc(sizeof(int) * EE);
    unsigned* epb = (unsigned*)alloc(sizeof(unsigned) * EE);
    unsigned short* G = (unsigned short*)alloc(sizeof(unsigned short) * 80 * (size_t)NN);
    float* bufA = (float*)alloc(sizeof(float) * 160 * (size_t)NN);
    float* bufB = (float*)alloc(sizeof(float) * 160 * (size_t)NN);

    // ---- CSR build (no global atomics anywhere) ----
    k_hist<<<NB_PART, 256, 0, stream>>>(dst, part_cnt);
    k_scanA<<<NPB, BS, 0, stream>>>(part_cnt, scan_out, bsums);
    k_scanB<<<1, 64, 0, stream>>>(bsums);
    k_scanC<<<cdiv(NP, BS), BS, 0, stream>>>(scan_out, bsums, bbase);
    k_part<<<NB_PART, 256, 0, stream>>>(src, dst, scan_out, epb);
    k_fine2<<<NBUCKET, 256, 0, stream>>>(bbase, epb, eidx, rowptr, dis);

    // ---- eg1 (3->160): AGG-first ----
    k_scale3<<<cdiv(3LL * NN, BS), BS, 0, stream>>>(x, dis, bufB);
    k_gather3d<0, false><<<cdiv(NN, BS), BS, 0, stream>>>(bufB, rowptr, eidx, dis, nullptr, bufA);
    k_mm_rowbcast<3, 160, 1><<<cdiv(NN * 40LL, BS), BS, 0, stream>>>(bufA, eg1_w, eg1_b, bufB);

    // ---- eg2 (160->80): MM-first, fp16 g ----
    k_mm_tiled<160, 80, 16, 5, 8, 32, 0, false, 2><<<cdiv(NN, 128), 256, 0, stream>>>(
        bufB, eg2_w, nullptr, (float*)G, dis);
    k_gatherh<80, 1, true><<<cdiv(NN * 20LL, BS), BS, 0, stream>>>(G, rowptr, eidx, dis, eg2_b, bufA);

    // ---- eg3 (80->40): MM-first, fp16 g ----
    k_mm_tiled<80, 40, 8, 5, 4, 40, 0, false, 2><<<cdiv(NN, 128), 256, 0, stream>>>(
        bufA, eg3_w, nullptr, (float*)G, dis);
    k_gatherh<40, 1, true><<<cdiv(NN * 10LL, BS), BS, 0, stream>>>(G, rowptr, eidx, dis, eg3_b, bufB);

    // ---- eg4 (40->20): MM-first, fp16 g ----
    k_mm_vec4<40, 20, 0, false, 2><<<cdiv((NN / 8) * 5LL, BS), BS, 0, stream>>>(
        bufB, eg4_w, nullptr, (float*)G, dis);
    k_gatherh<20, 1, true><<<cdiv(NN * 5LL, BS), BS, 0, stream>>>(G, rowptr, eidx, dis, eg4_b, bufA);

    // ---- dense latent stack ----
    k_mm_vec<20, 10, 1, true, 0><<<cdiv((NN / 8) * 10LL, BS), BS, 0, stream>>>(bufA, el1_w, el1_b, bufB, nullptr);
    k_mm_simple<10, 3, 0, true, 0><<<cdiv(3LL * NN, BS), BS, 0, stream>>>(bufB, el2_w, el2_b, bufA, nullptr);
    k_mm_simple<3, 10, 1, true, 0><<<cdiv(10LL * NN, BS), BS, 0, stream>>>(bufA, dl1_w, dl1_b, bufB, nullptr);
    // dl2 (10->20): relu output scaled by dis -> fp16 g for dg1's gather
    k_mm_simple<10, 20, 1, true, 2><<<cdiv(20LL * NN, BS), BS, 0, stream>>>(bufB, dl2_w, dl2_b, (float*)G, dis);

    // ---- dg1 (20->40): AGG-first ----
    k_gatherh<20, 0, false><<<cdiv(NN * 5LL, BS), BS, 0, stream>>>(G, rowptr, eidx, dis, nullptr, bufA);
    k_mm_vec4<20, 40, 1, true, 2><<<cdiv((NN / 8) * 10LL, BS), BS, 0, stream>>>(
        bufA, dg1_w, dg1_b, (float*)G, dis);

    // ---- dg2 (40->80): AGG-first ----
    k_gatherh<40, 0, false><<<cdiv(NN * 10LL, BS), BS, 0, stream>>>(G, rowptr, eidx, dis, nullptr, bufB);
    k_mm_tiled<40, 80, 16, 5, 8, 40, 1, true, 2><<<cdiv(NN, 128), 256, 0, stream>>>(
        bufB, dg2_w, dg2_b, (float*)G, dis);

    // ---- dg3 (80->160): AGG-first ----
    k_gatherh<80, 0, false><<<cdiv(NN * 20LL, BS), BS, 0, stream>>>(G, rowptr, eidx, dis, nullptr, bufA);
    k_mm_tiled<80, 160, 32, 5, 8, 40, 1, true, 0><<<cdiv(NN, 64), 256, 0, stream>>>(
        bufA, dg3_w, dg3_b, bufB, nullptr);

    // ---- dg4 (160->3): MM-first, tanh; mm writes dis-scaled fp32 g ----
    k_mm_vec<160, 3, 0, false, 1><<<cdiv((NN / 8) * 3LL, BS), BS, 0, stream>>>(bufB, dg4_w, nullptr, bufA, dis);
    k_gather3d<2, true><<<cdiv(NN, BS), BS, 0, stream>>>(bufA, rowptr, eidx, dis, dg4_b, out);
}

// Round 7
// 627.430 us; speedup vs baseline: 1.7808x; 1.1247x over previous
//
#include <hip/hip_runtime.h>
#include <hip/hip_fp16.h>
#include <math.h>

#define BS 256
static constexpr int NN = 100000;   // nodes
static constexpr int EE = 1600000;  // directed edges (excl. self loops)
static constexpr int BUCKET_SH = 7;                       // 128 nodes per bucket
static constexpr int NBUCKET = (NN + 127) >> BUCKET_SH;   // 782
static constexpr int NB_PART = 256;                       // partition blocks
static constexpr int CHUNK = EE / NB_PART;                // 6250 (exact)
static constexpr int NP = NBUCKET * NB_PART;              // 200192 scan elems
static constexpr int SCAN_ELEMS = 1024;
static constexpr int NPB = (NP + SCAN_ELEMS - 1) / SCAN_ELEMS;  // 196

static inline int cdiv(long long a, int b) { return (int)((a + b - 1) / b); }

// ---------------- helpers ----------------
template <int ACT>
__device__ __forceinline__ float act_f(float v) {
    if (ACT == 1) return fmaxf(v, 0.0f);
    if (ACT == 2) return tanhf(v);
    return v;
}

__device__ __forceinline__ unsigned short h16(float v) {
    return __half_as_ushort(__float2half(v));
}
__device__ __forceinline__ unsigned pack2h(float a, float b) {
    return (unsigned)h16(a) | ((unsigned)h16(b) << 16);
}
__device__ __forceinline__ float4 cvt4h(uint2 r) {
    float2 fa = __half22float2(*(const __half2*)&r.x);
    float2 fb = __half22float2(*(const __half2*)&r.y);
    return make_float4(fa.x, fa.y, fb.x, fb.y);
}

// OUTM: 0 = fp32, 1 = fp32*dis, 2 = fp16*dis, 3 = fp16 plain
template <int OUTM>
__device__ __forceinline__ void store1(float* out, size_t idx, float v, float dn) {
    if (OUTM == 0) out[idx] = v;
    else if (OUTM == 1) out[idx] = v * dn;
    else if (OUTM == 2) ((unsigned short*)out)[idx] = h16(v * dn);
    else ((unsigned short*)out)[idx] = h16(v);
}

// ---------------- CSR build: contention-free partitioned counting sort ----------------
__global__ __launch_bounds__(256) void k_hist(const int* __restrict__ dst,
                                              int* __restrict__ part_cnt) {
    __shared__ int h[NBUCKET];
    int b = blockIdx.x;
    for (int j = threadIdx.x; j < NBUCKET; j += 256) h[j] = 0;
    __syncthreads();
    int e0 = b * CHUNK;
    for (int k = threadIdx.x; k < CHUNK; k += 256)
        atomicAdd(&h[dst[e0 + k] >> BUCKET_SH], 1);
    __syncthreads();
    for (int j = threadIdx.x; j < NBUCKET; j += 256)
        part_cnt[j * NB_PART + b] = h[j];   // bucket-major for the scan
}

__global__ void k_scanA(const int* __restrict__ in, int* __restrict__ outp,
                        int* __restrict__ bsums) {
    __shared__ int lds[BS];
    int base = blockIdx.x * SCAN_ELEMS;
    int t = threadIdx.x;
    int v[4];
    int s = 0;
#pragma unroll
    for (int j = 0; j < 4; ++j) {
        int idx = base + t * 4 + j;
        v[j] = (idx < NP) ? in[idx] : 0;
        s += v[j];
    }
    lds[t] = s;
    __syncthreads();
    for (int off = 1; off < BS; off <<= 1) {
        int add = (t >= off) ? lds[t - off] : 0;
        __syncthreads();
        lds[t] += add;
        __syncthreads();
    }
    int run = lds[t] - s;
    if (t == BS - 1) bsums[blockIdx.x] = lds[BS - 1];
#pragma unroll
    for (int j = 0; j < 4; ++j) {
        int idx = base + t * 4 + j;
        if (idx < NP) outp[idx] = run;
        run += v[j];
    }
}

__global__ void k_scanB(int* __restrict__ bsums) {
    if (threadIdx.x == 0 && blockIdx.x == 0) {
        int acc = 0;
        for (int i = 0; i < NPB; ++i) {
            int t = bsums[i];
            bsums[i] = acc;
            acc += t;
        }
    }
}

__global__ void k_scanC(int* __restrict__ outp, const int* __restrict__ bsums,
                        int* __restrict__ bbase) {
    int i = blockIdx.x * BS + threadIdx.x;
    if (i < NP) {
        int v = outp[i] + bsums[i / SCAN_ELEMS];
        outp[i] = v;
        if ((i & (NB_PART - 1)) == 0) bbase[i / NB_PART] = v;
    }
    if (i == 0) bbase[NBUCKET] = EE;
}

__global__ __launch_bounds__(256) void k_part(const int* __restrict__ src,
                                              const int* __restrict__ dst,
                                              const int* __restrict__ scan_out,
                                              unsigned* __restrict__ epb) {
    __shared__ int cur[NBUCKET];
    int b = blockIdx.x;
    for (int j = threadIdx.x; j < NBUCKET; j += 256) cur[j] = scan_out[j * NB_PART + b];
    __syncthreads();
    int e0 = b * CHUNK;
    for (int k = threadIdx.x; k < CHUNK; k += 256) {
        int e = e0 + k;
        int d = dst[e];
        int s = src[e];
        int pos = atomicAdd(&cur[d >> BUCKET_SH], 1);
        epb[pos] = ((unsigned)(d & ((1 << BUCKET_SH) - 1)) << 17) | (unsigned)s;
    }
}

__global__ __launch_bounds__(256) void k_fine2(const int* __restrict__ bbase,
                                               const unsigned* __restrict__ epb,
                                               int* __restrict__ eidx,
                                               int* __restrict__ rowptr,
                                               float* __restrict__ dis) {
    __shared__ int hcnt[1 << BUCKET_SH];
    __shared__ int hoff[1 << BUCKET_SH];
    int b = blockIdx.x;
    int n0 = b << BUCKET_SH;
    int nloc = min(1 << BUCKET_SH, NN - n0);
    int t = threadIdx.x;
    if (t < (1 << BUCKET_SH)) hcnt[t] = 0;
    __syncthreads();
    int es = bbase[b], ee = bbase[b + 1];
    for (int k = es + t; k < ee; k += 256) atomicAdd(&hcnt[epb[k] >> 17], 1);
    __syncthreads();
    if (t < (1 << BUCKET_SH)) hoff[t] = hcnt[t];
    __syncthreads();
    for (int off = 1; off < (1 << BUCKET_SH); off <<= 1) {
        int add = (t >= off && t < (1 << BUCKET_SH)) ? hoff[t - off] : 0;
        __syncthreads();
        if (t < (1 << BUCKET_SH)) hoff[t] += add;
        __syncthreads();
    }
    if (t < nloc) {
        int excl = hoff[t] - hcnt[t];
        rowptr[n0 + t] = es + excl;
        dis[n0 + t] = rsqrtf((float)(hcnt[t] + 1));  // + self loop
    }
    __syncthreads();
    if (t < (1 << BUCKET_SH)) hoff[t] = es + hoff[t] - hcnt[t];  // cursors
    __syncthreads();
    for (int k = es + t; k < ee; k += 256) {
        unsigned p = epb[k];
        int pos = atomicAdd(&hoff[p >> 17], 1);
        eidx[pos] = (int)(p & 0x1FFFFu);
    }
    if (b == NBUCKET - 1 && t == 0) rowptr[NN] = EE;
}

// ---------------- gathers (4-way MLP-unrolled) ----------------
template <int C, int ACT, bool HASB>
__global__ void k_gatherh(const unsigned short* __restrict__ g, const int* __restrict__ rowptr,
                          const int* __restrict__ eidx, const float* __restrict__ dis,
                          const float* __restrict__ b, float* __restrict__ out) {
    static_assert(C % 4 == 0, "C%4");
    constexpr int V = C / 4;
    int t = blockIdx.x * BS + threadIdx.x;
    if (t >= NN * V) return;
    int n = t / V, v = t % V;
    const uint2* g2 = (const uint2*)g;
    float4 acc = cvt4h(g2[(size_t)n * V + v]);  // self term
    int rs = rowptr[n], re = rowptr[n + 1];
    int k = rs;
    for (; k + 4 <= re; k += 4) {
        int s0 = eidx[k + 0], s1 = eidx[k + 1], s2 = eidx[k + 2], s3 = eidx[k + 3];
        uint2 r0 = g2[(size_t)s0 * V + v];
        uint2 r1 = g2[(size_t)s1 * V + v];
        uint2 r2 = g2[(size_t)s2 * V + v];
        uint2 r3 = g2[(size_t)s3 * V + v];
        float4 h0 = cvt4h(r0), h1 = cvt4h(r1), h2 = cvt4h(r2), h3 = cvt4h(r3);
        acc.x += (h0.x + h1.x) + (h2.x + h3.x);
        acc.y += (h0.y + h1.y) + (h2.y + h3.y);
        acc.z += (h0.z + h1.z) + (h2.z + h3.z);
        acc.w += (h0.w + h1.w) + (h2.w + h3.w);
    }
    for (; k < re; ++k) {
        float4 hv = cvt4h(g2[(size_t)eidx[k] * V + v]);
        acc.x += hv.x; acc.y += hv.y; acc.z += hv.z; acc.w += hv.w;
    }
    float dn = dis[n];
    acc.x *= dn; acc.y *= dn; acc.z *= dn; acc.w *= dn;
    if (HASB) {
        float4 bb = ((const float4*)b)[v];
        acc.x += bb.x; acc.y += bb.y; acc.z += bb.z; acc.w += bb.w;
    }
    acc.x = act_f<ACT>(acc.x);
    acc.y = act_f<ACT>(acc.y);
    acc.z = act_f<ACT>(acc.z);
    acc.w = act_f<ACT>(acc.w);
    ((float4*)out)[(size_t)n * V + v] = acc;
}

// fp32 3-channel gather (input g = dis*h fp32), 4-way unrolled
template <int ACT, bool HASB>
__global__ void k_gather3d(const float* __restrict__ g, const int* __restrict__ rowptr,
                           const int* __restrict__ eidx, const float* __restrict__ dis,
                           const float* __restrict__ b, float* __restrict__ out) {
    int n = blockIdx.x * BS + threadIdx.x;
    if (n >= NN) return;
    const float* gp = g + (size_t)n * 3;
    float a0 = gp[0], a1 = gp[1], a2 = gp[2];
    int rs = rowptr[n], re = rowptr[n + 1];
    int k = rs;
    for (; k + 4 <= re; k += 4) {
        const float* q0 = g + (size_t)eidx[k + 0] * 3;
        const float* q1 = g + (size_t)eidx[k + 1] * 3;
        const float* q2 = g + (size_t)eidx[k + 2] * 3;
        const float* q3 = g + (size_t)eidx[k + 3] * 3;
        float b00 = q0[0], b01 = q0[1], b02 = q0[2];
        float b10 = q1[0], b11 = q1[1], b12 = q1[2];
        float b20 = q2[0], b21 = q2[1], b22 = q2[2];
        float b30 = q3[0], b31 = q3[1], b32 = q3[2];
        a0 += (b00 + b10) + (b20 + b30);
        a1 += (b01 + b11) + (b21 + b31);
        a2 += (b02 + b12) + (b22 + b32);
    }
    for (; k < re; ++k) {
        const float* gq = g + (size_t)eidx[k] * 3;
        a0 += gq[0]; a1 += gq[1]; a2 += gq[2];
    }
    float dn = dis[n];
    a0 *= dn; a1 *= dn; a2 *= dn;
    if (HASB) { a0 += b[0]; a1 += b[1]; a2 += b[2]; }
    float* op = out + (size_t)n * 3;
    op[0] = act_f<ACT>(a0);
    op[1] = act_f<ACT>(a1);
    op[2] = act_f<ACT>(a2);
}

// prescale: g = x * dis[n] (3ch fp32)
__global__ void k_scale3(const float* __restrict__ x, const float* __restrict__ dis,
                         float* __restrict__ g) {
    int i = blockIdx.x * BS + threadIdx.x;
    if (i < NN * 3) g[i] = x[i] * dis[i / 3];
}

// ---------------- LDS-tiled SGEMM (INH: fp16 input) ----------------
template <int CIN, int COUT, int TC, int TN, int TM, int BK, int ACT, bool HASB, int OUTM, bool INH>
__global__ __launch_bounds__(256) void k_mm_tiled(const float* __restrict__ x,
                                                  const float* __restrict__ w,
                                                  const float* __restrict__ b,
                                                  float* __restrict__ out,
                                                  const float* __restrict__ dis) {
    constexpr int TR = 256 / TC;
    constexpr int BM = TR * TM;
    constexpr int LDA = BM + 4;
    constexpr int CHUNKS = CIN / BK;
    constexpr int BK4 = BK / 4;
    constexpr int CIN4 = CIN / 4;
    static_assert(TC * TN == COUT, "cols");
    static_assert(CIN % BK == 0 && BK % 4 == 0, "bk");
    static_assert(TM == 4 || TM == 8, "tm");
    __shared__ float As[BK * LDA];
    __shared__ float Ws[BK * COUT];
    const int tid = threadIdx.x;
    const int tc = tid % TC, tr = tid / TC;
    const int n0 = blockIdx.x * BM;

    float acc[TM][TN];
#pragma unroll
    for (int r = 0; r < TM; ++r)
#pragma unroll
        for (int j = 0; j < TN; ++j) acc[r][j] = HASB ? b[tc * TN + j] : 0.0f;

    const float4* x4 = (const float4*)x;
    const uint2* xh = (const uint2*)x;
    const float4* w4 = (const float4*)w;

    for (int ch = 0; ch < CHUNKS; ++ch) {
        const int kb4 = ch * BK4;
        if (ch) __syncthreads();
        for (int i = tid; i < BM * BK4; i += 256) {
            int r = i / BK4, k4 = i % BK4;
            int row = n0 + r;
            float4 v = make_float4(0.f, 0.f, 0.f, 0.f);
            if (row < NN) {
                if (INH) v = cvt4h(xh[(size_t)row * CIN4 + kb4 + k4]);
                else v = x4[(size_t)row * CIN4 + kb4 + k4];
            }
            int base = (4 * k4) * LDA + r;
            As[base] = v.x;
            As[base + LDA] = v.y;
            As[base + 2 * LDA] = v.z;
            As[base + 3 * LDA] = v.w;
        }
        for (int i = tid; i < BK * COUT / 4; i += 256) {
            ((float4*)Ws)[i] = w4[(size_t)kb4 * COUT + i];
        }
        __syncthreads();
#pragma unroll 4
        for (int k = 0; k < BK; ++k) {
            float a[TM];
            *(float4*)&a[0] = *(const float4*)&As[k * LDA + tr * TM];
            if (TM == 8) *(float4*)&a[4] = *(const float4*)&As[k * LDA + tr * TM + 4];
            float wr[TN];
#pragma unroll
            for (int j = 0; j < TN; ++j) wr[j] = Ws[k * COUT + tc * TN + j];
#pragma unroll
            for (int r = 0; r < TM; ++r)
#pragma unroll
                for (int j = 0; j < TN; ++j) acc[r][j] = fmaf(a[r], wr[j], acc[r][j]);
        }
    }
#pragma unroll
    for (int r = 0; r < TM; ++r) {
        int row = n0 + tr * TM + r;
        if (row < NN) {
            float dn = (OUTM == 1 || OUTM == 2) ? dis[row] : 0.0f;
            size_t base = (size_t)row * COUT + tc * TN;
#pragma unroll
            for (int j = 0; j < TN; ++j) store1<OUTM>(out, base + j, act_f<ACT>(acc[r][j]), dn);
        }
    }
}

// ---------------- mm_vec4: TM=8 rows x 4 cols per thread ----------------
template <int CIN, int COUT, int ACT, bool HASB, int OUTM>
__global__ void k_mm_vec4(const float* __restrict__ x, const float* __restrict__ w,
                          const float* __restrict__ b, float* __restrict__ out,
                          const float* __restrict__ dis) {
    static_assert(CIN % 4 == 0 && COUT % 4 == 0, "align");
    constexpr int TM = 8;
    constexpr int CIN4 = CIN / 4;
    constexpr int COUT4 = COUT / 4;
    constexpr int RG = NN / TM;
    int i = blockIdx.x * BS + threadIdx.x;
    if (i >= RG * COUT4) return;
    int c4 = i % COUT4;
    int n0 = (i / COUT4) * TM;
    const float4* x4 = (const float4*)x;
    const float4* w4 = (const float4*)w;
    float4 acc[TM];
    float4 bb = HASB ? ((const float4*)b)[c4] : make_float4(0.f, 0.f, 0.f, 0.f);
#pragma unroll
    for (int r = 0; r < TM; ++r) acc[r] = bb;
    for (int k4 = 0; k4 < CIN4; ++k4) {
        float4 wv[4];
#pragma unroll
        for (int j = 0; j < 4; ++j) wv[j] = w4[(size_t)(4 * k4 + j) * COUT4 + c4];
#pragma unroll
        for (int r = 0; r < TM; ++r) {
            float4 xv = x4[(size_t)(n0 + r) * CIN4 + k4];
            acc[r].x = fmaf(xv.x, wv[0].x, fmaf(xv.y, wv[1].x, fmaf(xv.z, wv[2].x, fmaf(xv.w, wv[3].x, acc[r].x))));
            acc[r].y = fmaf(xv.x, wv[0].y, fmaf(xv.y, wv[1].y, fmaf(xv.z, wv[2].y, fmaf(xv.w, wv[3].y, acc[r].y))));
            acc[r].z = fmaf(xv.x, wv[0].z, fmaf(xv.y, wv[1].z, fmaf(xv.z, wv[2].z, fmaf(xv.w, wv[3].z, acc[r].z))));
            acc[r].w = fmaf(xv.x, wv[0].w, fmaf(xv.y, wv[1].w, fmaf(xv.z, wv[2].w, fmaf(xv.w, wv[3].w, acc[r].w))));
        }
    }
#pragma unroll
    for (int r = 0; r < TM; ++r) {
        float vx = act_f<ACT>(acc[r].x), vy = act_f<ACT>(acc[r].y);
        float vz = act_f<ACT>(acc[r].z), vw = act_f<ACT>(acc[r].w);
        size_t gi = (size_t)(n0 + r) * COUT4 + c4;
        if (OUTM == 2) {
            float dn = dis[n0 + r];
            uint2 u;
            u.x = pack2h(vx * dn, vy * dn);
            u.y = pack2h(vz * dn, vw * dn);
            ((uint2*)out)[gi] = u;
        } else if (OUTM == 1) {
            float dn = dis[n0 + r];
            ((float4*)out)[gi] = make_float4(vx * dn, vy * dn, vz * dn, vw * dn);
        } else {
            ((float4*)out)[gi] = make_float4(vx, vy, vz, vw);
        }
    }
}

// ---------------- small-CIN matmul, vectorized output (fp32 or fp16) ----------------
template <int CIN, int COUT, int ACT, int OUTM>
__global__ void k_mm_rowbcast(const float* __restrict__ x, const float* __restrict__ w,
                              const float* __restrict__ b, float* __restrict__ out) {
    static_assert(COUT % 4 == 0, "c4");
    constexpr int COUT4 = COUT / 4;
    int i = blockIdx.x * BS + threadIdx.x;
    if (i >= NN * COUT4) return;
    int n = i / COUT4, c4 = i % COUT4;
    const float4* w4 = (const float4*)w;
    float4 acc = ((const float4*)b)[c4];
    const float* xr = x + (size_t)n * CIN;
#pragma unroll
    for (int ci = 0; ci < CIN; ++ci) {
        float xv = xr[ci];
        float4 wv = w4[ci * COUT4 + c4];
        acc.x = fmaf(xv, wv.x, acc.x);
        acc.y = fmaf(xv, wv.y, acc.y);
        acc.z = fmaf(xv, wv.z, acc.z);
        acc.w = fmaf(xv, wv.w, acc.w);
    }
    acc.x = act_f<ACT>(acc.x); acc.y = act_f<ACT>(acc.y);
    acc.z = act_f<ACT>(acc.z); acc.w = act_f<ACT>(acc.w);
    if (OUTM == 3) {
        uint2 u;
        u.x = pack2h(acc.x, acc.y);
        u.y = pack2h(acc.z, acc.w);
        ((uint2*)out)[(size_t)n * COUT4 + c4] = u;
    } else {
        ((float4*)out)[(size_t)n * COUT4 + c4] = acc;
    }
}

// ---------------- simple matmul (tiny layers) ----------------
template <int CIN, int COUT, int ACT, bool HASB, int OUTM>
__global__ void k_mm_simple(const float* __restrict__ x, const float* __restrict__ w,
                            const float* __restrict__ b, float* __restrict__ out,
                            const float* __restrict__ dis) {
    int i = blockIdx.x * BS + threadIdx.x;
    if (i >= NN * COUT) return;
    int n = i / COUT, c = i % COUT;
    const float* xr = x + (size_t)n * CIN;
    float acc = HASB ? b[c] : 0.0f;
#pragma unroll
    for (int ci = 0; ci < CIN; ++ci) acc = fmaf(xr[ci], w[ci * COUT + c], acc);
    float dn = (OUTM == 1 || OUTM == 2) ? dis[n] : 0.0f;
    store1<OUTM>(out, (size_t)i, act_f<ACT>(acc), dn);
}

// ---------------- vec matmul (odd COUT) ----------------
template <int CIN, int COUT, int ACT, bool HASB, int OUTM>
__global__ void k_mm_vec(const float* __restrict__ x, const float* __restrict__ w,
                         const float* __restrict__ b, float* __restrict__ out,
                         const float* __restrict__ dis) {
    static_assert(CIN % 4 == 0, "CIN%4");
    constexpr int TM = 8;
    constexpr int CIN4 = CIN / 4;
    constexpr int RG = NN / TM;
    int i = blockIdx.x * BS + threadIdx.x;
    if (i >= RG * COUT) return;
    int c = i % COUT;
    int n0 = (i / COUT) * TM;
    float acc[TM];
    float bb = HASB ? b[c] : 0.0f;
#pragma unroll
    for (int r = 0; r < TM; ++r) acc[r] = bb;
    const float4* x4 = (const float4*)x;
    for (int k = 0; k < CIN4; ++k) {
        float w0 = w[(4 * k + 0) * COUT + c];
        float w1 = w[(4 * k + 1) * COUT + c];
        float w2 = w[(4 * k + 2) * COUT + c];
        float w3 = w[(4 * k + 3) * COUT + c];
#pragma unroll
        for (int r = 0; r < TM; ++r) {
            float4 xv = x4[(size_t)(n0 + r) * CIN4 + k];
            acc[r] = fmaf(xv.x, w0, fmaf(xv.y, w1, fmaf(xv.z, w2, fmaf(xv.w, w3, acc[r]))));
        }
    }
#pragma unroll
    for (int r = 0; r < TM; ++r) {
        int row = n0 + r;
        float dn = (OUTM == 1 || OUTM == 2) ? dis[row] : 0.0f;
        store1<OUTM>(out, (size_t)row * COUT + c, act_f<ACT>(acc[r]), dn);
    }
}

extern "C" void kernel_launch(void* const* d_in, const int* in_sizes, int n_in,
                              void* d_out, int out_size, void* d_ws, size_t ws_size,
                              hipStream_t stream) {
    const float* x = (const float*)d_in[0];
    const int* ei = (const int*)d_in[1];
    const int* src = ei;
    const int* dst = ei + EE;
    const float* eg1_w = (const float*)d_in[2];  const float* eg1_b = (const float*)d_in[3];
    const float* eg2_w = (const float*)d_in[4];  const float* eg2_b = (const float*)d_in[5];
    const float* eg3_w = (const float*)d_in[6];  const float* eg3_b = (const float*)d_in[7];
    const float* eg4_w = (const float*)d_in[8];  const float* eg4_b = (const float*)d_in[9];
    const float* el1_w = (const float*)d_in[10]; const float* el1_b = (const float*)d_in[11];
    const float* el2_w = (const float*)d_in[12]; const float* el2_b = (const float*)d_in[13];
    const float* dl1_w = (const float*)d_in[14]; const float* dl1_b = (const float*)d_in[15];
    const float* dl2_w = (const float*)d_in[16]; const float* dl2_b = (const float*)d_in[17];
    const float* dg1_w = (const float*)d_in[18]; const float* dg1_b = (const float*)d_in[19];
    const float* dg2_w = (const float*)d_in[20]; const float* dg2_b = (const float*)d_in[21];
    const float* dg3_w = (const float*)d_in[22]; const float* dg3_b = (const float*)d_in[23];
    const float* dg4_w = (const float*)d_in[24]; const float* dg4_b = (const float*)d_in[25];
    float* out = (float*)d_out;

    char* ws = (char*)d_ws;
    size_t off = 0;
    auto alloc = [&](size_t bytes) {
        void* p = ws + off;
        off += (bytes + 15) & ~(size_t)15;
        return p;
    };
    int* part_cnt = (int*)alloc(sizeof(int) * NP);
    int* scan_out = (int*)alloc(sizeof(int) * NP);
    int* bsums    = (int*)alloc(sizeof(int) * NPB);
    int* bbase    = (int*)alloc(sizeof(int) * (NBUCKET + 1));
    int* rowptr   = (int*)alloc(sizeof(int) * (NN + 1));
    float* dis    = (float*)alloc(sizeof(float) * NN);
    int* eidx     = (int*)alloc(sizeof(int) * EE);
    unsigned* epb = (unsigned*)alloc(sizeof(unsigned) * EE);
    unsigned short* G = (unsigned short*)alloc(sizeof(unsigned short) * 80 * (size_t)NN);
    float* bufA = (float*)alloc(sizeof(float) * 160 * (size_t)NN);
    float* bufB = (float*)alloc(sizeof(float) * 160 * (size_t)NN);

    // ---- CSR build (no global atomics anywhere) ----
    k_hist<<<NB_PART, 256, 0, stream>>>(dst, part_cnt);
    k_scanA<<<NPB, BS, 0, stream>>>(part_cnt, scan_out, bsums);
    k_scanB<<<1, 64, 0, stream>>>(bsums);
    k_scanC<<<cdiv(NP, BS), BS, 0, stream>>>(scan_out, bsums, bbase);
    k_part<<<NB_PART, 256, 0, stream>>>(src, dst, scan_out, epb);
    k_fine2<<<NBUCKET, 256, 0, stream>>>(bbase, epb, eidx, rowptr, dis);

    // ---- eg1 (3->160): AGG-first; output fp16 (plain) into bufB ----
    k_scale3<<<cdiv(3LL * NN, BS), BS, 0, stream>>>(x, dis, bufB);
    k_gather3d<0, false><<<cdiv(NN, BS), BS, 0, stream>>>(bufB, rowptr, eidx, dis, nullptr, bufA);
    k_mm_rowbcast<3, 160, 1, 3><<<cdiv(NN * 40LL, BS), BS, 0, stream>>>(bufA, eg1_w, eg1_b, bufB);

    // ---- eg2 (160->80): MM-first (fp16 in), fp16*dis out -> G ----
    k_mm_tiled<160, 80, 16, 5, 8, 32, 0, false, 2, true><<<cdiv(NN, 128), 256, 0, stream>>>(
        bufB, eg2_w, nullptr, (float*)G, dis);
    k_gatherh<80, 1, true><<<cdiv(NN * 20LL, BS), BS, 0, stream>>>(G, rowptr, eidx, dis, eg2_b, bufA);

    // ---- eg3 (80->40): MM-first, fp16 g ----
    k_mm_tiled<80, 40, 8, 5, 4, 40, 0, false, 2, false><<<cdiv(NN, 128), 256, 0, stream>>>(
        bufA, eg3_w, nullptr, (float*)G, dis);
    k_gatherh<40, 1, true><<<cdiv(NN * 10LL, BS), BS, 0, stream>>>(G, rowptr, eidx, dis, eg3_b, bufB);

    // ---- eg4 (40->20): MM-first, fp16 g ----
    k_mm_vec4<40, 20, 0, false, 2><<<cdiv((NN / 8) * 5LL, BS), BS, 0, stream>>>(
        bufB, eg4_w, nullptr, (float*)G, dis);
    k_gatherh<20, 1, true><<<cdiv(NN * 5LL, BS), BS, 0, stream>>>(G, rowptr, eidx, dis, eg4_b, bufA);

    // ---- dense latent stack ----
    k_mm_vec<20, 10, 1, true, 0><<<cdiv((NN / 8) * 10LL, BS), BS, 0, stream>>>(bufA, el1_w, el1_b, bufB, nullptr);
    k_mm_simple<10, 3, 0, true, 0><<<cdiv(3LL * NN, BS), BS, 0, stream>>>(bufB, el2_w, el2_b, bufA, nullptr);
    k_mm_simple<3, 10, 1, true, 0><<<cdiv(10LL * NN, BS), BS, 0, stream>>>(bufA, dl1_w, dl1_b, bufB, nullptr);
    // dl2 (10->20): relu output scaled by dis -> fp16 g for dg1's gather
    k_mm_simple<10, 20, 1, true, 2><<<cdiv(20LL * NN, BS), BS, 0, stream>>>(bufB, dl2_w, dl2_b, (float*)G, dis);

    // ---- dg1 (20->40): AGG-first ----
    k_gatherh<20, 0, false><<<cdiv(NN * 5LL, BS), BS, 0, stream>>>(G, rowptr, eidx, dis, nullptr, bufA);
    k_mm_vec4<20, 40, 1, true, 2><<<cdiv((NN / 8) * 10LL, BS), BS, 0, stream>>>(
        bufA, dg1_w, dg1_b, (float*)G, dis);

    // ---- dg2 (40->80): AGG-first ----
    k_gatherh<40, 0, false><<<cdiv(NN * 10LL, BS), BS, 0, stream>>>(G, rowptr, eidx, dis, nullptr, bufB);
    k_mm_tiled<40, 80, 16, 5, 8, 40, 1, true, 2, false><<<cdiv(NN, 128), 256, 0, stream>>>(
        bufB, dg2_w, dg2_b, (float*)G, dis);

    // ---- dg3 (80->160): AGG-first ----
    k_gatherh<80, 0, false><<<cdiv(NN * 20LL, BS), BS, 0, stream>>>(G, rowptr, eidx, dis, nullptr, bufA);
    k_mm_tiled<80, 160, 32, 5, 8, 40, 1, true, 0, false><<<cdiv(NN, 64), 256, 0, stream>>>(
        bufA, dg3_w, dg3_b, bufB, nullptr);

    // ---- dg4 (160->3): MM-first, tanh; mm writes dis-scaled fp32 g ----
    k_mm_vec<160, 3, 0, false, 1><<<cdiv((NN / 8) * 3LL, BS), BS, 0, stream>>>(bufB, dg4_w, nullptr, bufA, dis);
    k_gather3d<2, true><<<cdiv(NN, BS), BS, 0, stream>>>(bufA, rowptr, eidx, dis, dg4_b, out);
}